// Round 1
// baseline (299.612 us; speedup 1.0000x reference)
//
#include <hip/hip_runtime.h>
#include <hip/hip_bf16.h>
#include <cstdint>
#include <cstddef>

#define NB 4
#define CIN 256
#define CHID 128
#define HEADS 4
#define CHEAD 32
#define NPOS 4096      // 64*64
#define BH 16          // NB*HEADS
#define NTOT 16384     // NB*NPOS
#define QKV_O 384
#define QSCALE 0.17677669529663687f  // 32^-0.5

typedef float f32x4 __attribute__((ext_vector_type(4)));
typedef short s16x8 __attribute__((ext_vector_type(8)));

static __device__ __forceinline__ unsigned short f2bf(float f) {
    union { float f; unsigned u; } v; v.f = f;
    unsigned r = v.u + 0x7FFFu + ((v.u >> 16) & 1u);
    return (unsigned short)(r >> 16);
}

// ---------------- kernel 1: convert weights to bf16 ----------------
__global__ void k_convert_w(const float* __restrict__ wqkv, const float* __restrict__ wout,
                            unsigned short* __restrict__ wqkv_bf, unsigned short* __restrict__ wout_bf) {
    int i = blockIdx.x * 256 + threadIdx.x;
    if (i < QKV_O * CIN) wqkv_bf[i] = f2bf(wqkv[i]);
    if (i < CIN * CHID)  wout_bf[i]  = f2bf(wout[i]);
}

// ---------------- kernel 2: transpose x [b][256][4096] f32 -> xT [b*4096][256] bf16 ----------------
__global__ __launch_bounds__(256) void k_transpose_x(const float* __restrict__ x,
                                                     unsigned short* __restrict__ xT) {
    __shared__ float tile[32][33];
    const int ntiles = NPOS / 32;   // 128
    const int ctiles = CIN / 32;    // 8
    int b   = blockIdx.x / (ntiles * ctiles);
    int rem = blockIdx.x % (ntiles * ctiles);
    int ct = rem / ntiles;
    int nt = rem % ntiles;
    int c0 = ct * 32, n0 = nt * 32;
    int tc = threadIdx.x / 32;      // 0..7
    int tn = threadIdx.x % 32;
    const float* xb = x + (size_t)b * CIN * NPOS;
#pragma unroll
    for (int it = 0; it < 4; ++it) {
        int c = tc + it * 8;
        tile[c][tn] = xb[(size_t)(c0 + c) * NPOS + n0 + tn];
    }
    __syncthreads();
    unsigned short* xTb = xT + (size_t)b * NPOS * CIN;
#pragma unroll
    for (int it = 0; it < 4; ++it) {
        int n = tc + it * 8;
        xTb[(size_t)(n0 + n) * CIN + c0 + tn] = f2bf(tile[tn][n]);
    }
}

// ---------------- kernel 3: QKV projection GEMM (bf16 MFMA) ----------------
// C[o][nG] = sum_c wqkv[o][c] * xT[nG][c];  o<128 -> Q (scaled), o<256 -> K, else -> Vt
__global__ __launch_bounds__(256) void k_qkv(const unsigned short* __restrict__ wq,
                                             const unsigned short* __restrict__ xT,
                                             unsigned short* __restrict__ Q,
                                             unsigned short* __restrict__ K,
                                             unsigned short* __restrict__ V) {
    int mt = blockIdx.x % (QKV_O / 64);   // 0..5
    int nt = blockIdx.x / (QKV_O / 64);   // 0..255
    int wid = threadIdx.x >> 6, lane = threadIdx.x & 63;
    int quad = lane >> 4, low4 = lane & 15;
    int mw = mt * 64 + wid * 16;
    int n0 = nt * 64;
    f32x4 acc[4] = {};
    for (int k0 = 0; k0 < CIN; k0 += 32) {
        s16x8 a = *(const s16x8*)(wq + (size_t)(mw + low4) * CIN + k0 + quad * 8);
#pragma unroll
        for (int t = 0; t < 4; ++t) {
            s16x8 bfr = *(const s16x8*)(xT + (size_t)(n0 + t * 16 + low4) * CIN + k0 + quad * 8);
            acc[t] = __builtin_amdgcn_mfma_f32_16x16x32_bf16(a, bfr, acc[t], 0, 0, 0);
        }
    }
#pragma unroll
    for (int t = 0; t < 4; ++t) {
        int nG = n0 + t * 16 + low4;
        int b = nG >> 12, n = nG & 4095;
#pragma unroll
        for (int r = 0; r < 4; ++r) {
            int o = mw + quad * 4 + r;
            float v = acc[t][r];
            if (o < 128) {
                int head = o >> 5, ch = o & 31;
                Q[((size_t)(b * 4 + head) * NPOS + n) * 32 + ch] = f2bf(v * QSCALE);
            } else if (o < 256) {
                int o2 = o - 128; int head = o2 >> 5, ch = o2 & 31;
                K[((size_t)(b * 4 + head) * NPOS + n) * 32 + ch] = f2bf(v);
            } else {
                int o2 = o - 256; int head = o2 >> 5, ch = o2 & 31;
                V[((size_t)((b * 4 + head) * 32 + ch)) * NPOS + n] = f2bf(v);
            }
        }
    }
}

// ---------------- kernel 4: attention (flash-style, no-max softmax) ----------------
// grid: bh(16) x qtile(64);  block: 4 waves, wave handles 16 queries
__global__ __launch_bounds__(256) void k_attn(const unsigned short* __restrict__ Q,
                                              const unsigned short* __restrict__ K,
                                              const unsigned short* __restrict__ V,
                                              unsigned short* __restrict__ attnO) {
    __shared__ unsigned short pT[4][16 * 48];   // per-wave 16q x 32k tile, rows padded to 48 shorts
    int bh = blockIdx.x >> 6;
    int qt = blockIdx.x & 63;
    int wid = threadIdx.x >> 6, lane = threadIdx.x & 63;
    int quad = lane >> 4, low4 = lane & 15;
    int q0 = qt * 64 + wid * 16;
    const unsigned short* Qp = Q + (size_t)bh * NPOS * 32;
    const unsigned short* Kp = K + (size_t)bh * NPOS * 32;
    const unsigned short* Vp = V + (size_t)bh * 32 * NPOS;

    s16x8 aq = *(const s16x8*)(Qp + (size_t)(q0 + low4) * 32 + quad * 8);
    f32x4 oacc0 = {}, oacc1 = {}, lsum = {};
    unsigned short* myP = &pT[wid][0];

    for (int k0 = 0; k0 < NPOS; k0 += 32) {
        f32x4 s0 = {}, s1 = {};
        s16x8 bk0 = *(const s16x8*)(Kp + (size_t)(k0 + low4) * 32 + quad * 8);
        s16x8 bk1 = *(const s16x8*)(Kp + (size_t)(k0 + 16 + low4) * 32 + quad * 8);
        s0 = __builtin_amdgcn_mfma_f32_16x16x32_bf16(aq, bk0, s0, 0, 0, 0);
        s1 = __builtin_amdgcn_mfma_f32_16x16x32_bf16(aq, bk1, s1, 0, 0, 0);
#pragma unroll
        for (int r = 0; r < 4; ++r) {
            float p0 = __expf(s0[r]);
            float p1 = __expf(s1[r]);
            lsum[r] += p0 + p1;
            myP[(quad * 4 + r) * 48 + low4]      = f2bf(p0);
            myP[(quad * 4 + r) * 48 + low4 + 16] = f2bf(p1);
        }
        __syncthreads();   // RAW: P writes visible to the wave's own b128 read (bulletproof)
        s16x8 ap  = *(const s16x8*)(myP + low4 * 48 + quad * 8);
        s16x8 bv0 = *(const s16x8*)(Vp + (size_t)(low4)      * NPOS + k0 + quad * 8);
        s16x8 bv1 = *(const s16x8*)(Vp + (size_t)(low4 + 16) * NPOS + k0 + quad * 8);
        oacc0 = __builtin_amdgcn_mfma_f32_16x16x32_bf16(ap, bv0, oacc0, 0, 0, 0);
        oacc1 = __builtin_amdgcn_mfma_f32_16x16x32_bf16(ap, bv1, oacc1, 0, 0, 0);
        __builtin_amdgcn_wave_barrier();  // WAR: keep next iter's P writes after this read
    }

    // reduce lsum over the 16 lanes sharing a quad (keys mod 16)
#pragma unroll
    for (int r = 0; r < 4; ++r) {
        float v = lsum[r];
        v += __shfl_xor(v, 1);
        v += __shfl_xor(v, 2);
        v += __shfl_xor(v, 4);
        v += __shfl_xor(v, 8);
        lsum[r] = v;
    }
    int b = bh >> 2, head = bh & 3;
#pragma unroll
    for (int r = 0; r < 4; ++r) {
        float inv = 1.0f / lsum[r];
        int n = q0 + quad * 4 + r;
        size_t base = ((size_t)(b * NPOS + n)) * CHID + head * 32;
        attnO[base + low4]      = f2bf(oacc0[r] * inv);
        attnO[base + low4 + 16] = f2bf(oacc1[r] * inv);
    }
}

// ---------------- kernel 5: output projection GEMM + bias ----------------
__global__ __launch_bounds__(256) void k_out(const unsigned short* __restrict__ wo,
                                             const unsigned short* __restrict__ attnO,
                                             const float* __restrict__ bias,
                                             float* __restrict__ out) {
    int mt = blockIdx.x & 3;        // 256/64
    int nt = blockIdx.x >> 2;       // 0..255
    int wid = threadIdx.x >> 6, lane = threadIdx.x & 63;
    int quad = lane >> 4, low4 = lane & 15;
    int mw = mt * 64 + wid * 16;
    int n0 = nt * 64;
    f32x4 acc[4] = {};
#pragma unroll
    for (int k0 = 0; k0 < CHID; k0 += 32) {
        s16x8 a = *(const s16x8*)(wo + (size_t)(mw + low4) * CHID + k0 + quad * 8);
#pragma unroll
        for (int t = 0; t < 4; ++t) {
            s16x8 bfr = *(const s16x8*)(attnO + (size_t)(n0 + t * 16 + low4) * CHID + k0 + quad * 8);
            acc[t] = __builtin_amdgcn_mfma_f32_16x16x32_bf16(a, bfr, acc[t], 0, 0, 0);
        }
    }
#pragma unroll
    for (int t = 0; t < 4; ++t) {
        int nG = n0 + t * 16 + low4;
        int b = nG >> 12, n = nG & 4095;
#pragma unroll
        for (int r = 0; r < 4; ++r) {
            int o = mw + quad * 4 + r;
            out[((size_t)(b * CIN + o)) * NPOS + n] = acc[t][r] + bias[o];
        }
    }
}

extern "C" void kernel_launch(void* const* d_in, const int* in_sizes, int n_in,
                              void* d_out, int out_size, void* d_ws, size_t ws_size,
                              hipStream_t stream) {
    const float* x    = (const float*)d_in[0];
    const float* wqkv = (const float*)d_in[1];
    const float* wout = (const float*)d_in[2];
    const float* bout = (const float*)d_in[3];
    float* out = (float*)d_out;

    unsigned short* Q       = (unsigned short*)d_ws;
    unsigned short* K       = Q + (size_t)BH * NPOS * 32;       // +4 MB
    unsigned short* V       = K + (size_t)BH * NPOS * 32;       // +4 MB
    unsigned short* attnO   = V + (size_t)BH * 32 * NPOS;       // +4 MB
    unsigned short* xT      = attnO + (size_t)NTOT * CHID;      // +4 MB
    unsigned short* wqkv_bf = xT + (size_t)NTOT * CIN;          // +8 MB
    unsigned short* wout_bf = wqkv_bf + QKV_O * CIN;            // +192 KB
    // total ~24.3 MB of ws

    k_convert_w<<<(QKV_O * CIN + 255) / 256, 256, 0, stream>>>(wqkv, wout, wqkv_bf, wout_bf);
    k_transpose_x<<<NB * (CIN / 32) * (NPOS / 32), 256, 0, stream>>>(x, xT);
    k_qkv<<<(QKV_O / 64) * (NTOT / 64), 256, 0, stream>>>(wqkv_bf, xT, Q, K, V);
    k_attn<<<BH * (NPOS / 64), 256, 0, stream>>>(Q, K, V, attnO);
    k_out<<<(CIN / 64) * (NTOT / 64), 256, 0, stream>>>(wout_bf, attnO, bout, out);
}

// Round 2
// 292.786 us; speedup vs baseline: 1.0233x; 1.0233x over previous
//
#include <hip/hip_runtime.h>
#include <hip/hip_bf16.h>
#include <cstdint>
#include <cstddef>

#define NB 4
#define CIN 256
#define CHID 128
#define HEADS 4
#define CHEAD 32
#define NPOS 4096      // 64*64
#define BH 16          // NB*HEADS
#define NTOT 16384     // NB*NPOS
#define QKV_O 384
#define QSCALE 0.17677669529663687f  // 32^-0.5

typedef float f32x4 __attribute__((ext_vector_type(4)));
typedef short s16x8 __attribute__((ext_vector_type(8)));

static __device__ __forceinline__ unsigned short f2bf(float f) {
    union { float f; unsigned u; } v; v.f = f;
    unsigned r = v.u + 0x7FFFu + ((v.u >> 16) & 1u);
    return (unsigned short)(r >> 16);
}

// ---------------- kernel 1: convert weights to bf16 ----------------
__global__ void k_convert_w(const float* __restrict__ wqkv, const float* __restrict__ wout,
                            unsigned short* __restrict__ wqkv_bf, unsigned short* __restrict__ wout_bf) {
    int i = blockIdx.x * 256 + threadIdx.x;
    if (i < QKV_O * CIN) wqkv_bf[i] = f2bf(wqkv[i]);
    if (i < CIN * CHID)  wout_bf[i]  = f2bf(wout[i]);
}

// ---------------- kernel 2: transpose x [b][256][4096] f32 -> xT [b*4096][256] bf16 ----------------
__global__ __launch_bounds__(256) void k_transpose_x(const float* __restrict__ x,
                                                     unsigned short* __restrict__ xT) {
    __shared__ float tile[32][33];
    const int ntiles = NPOS / 32;   // 128
    const int ctiles = CIN / 32;    // 8
    int b   = blockIdx.x / (ntiles * ctiles);
    int rem = blockIdx.x % (ntiles * ctiles);
    int ct = rem / ntiles;
    int nt = rem % ntiles;
    int c0 = ct * 32, n0 = nt * 32;
    int tc = threadIdx.x / 32;      // 0..7
    int tn = threadIdx.x % 32;
    const float* xb = x + (size_t)b * CIN * NPOS;
#pragma unroll
    for (int it = 0; it < 4; ++it) {
        int c = tc + it * 8;
        tile[c][tn] = xb[(size_t)(c0 + c) * NPOS + n0 + tn];
    }
    __syncthreads();
    unsigned short* xTb = xT + (size_t)b * NPOS * CIN;
#pragma unroll
    for (int it = 0; it < 4; ++it) {
        int n = tc + it * 8;
        xTb[(size_t)(n0 + n) * CIN + c0 + tn] = f2bf(tile[tn][n]);
    }
}

// ---------------- kernel 3: QKV projection GEMM (bf16 MFMA) ----------------
// C[o][nG] = sum_c wqkv[o][c] * xT[nG][c];  o<128 -> Q (scaled), o<256 -> K, else -> Vt
__global__ __launch_bounds__(256) void k_qkv(const unsigned short* __restrict__ wq,
                                             const unsigned short* __restrict__ xT,
                                             unsigned short* __restrict__ Q,
                                             unsigned short* __restrict__ K,
                                             unsigned short* __restrict__ V) {
    int mt = blockIdx.x % (QKV_O / 64);   // 0..5
    int nt = blockIdx.x / (QKV_O / 64);   // 0..255
    int wid = threadIdx.x >> 6, lane = threadIdx.x & 63;
    int quad = lane >> 4, low4 = lane & 15;
    int mw = mt * 64 + wid * 16;
    int n0 = nt * 64;
    f32x4 acc[4] = {};
    for (int k0 = 0; k0 < CIN; k0 += 32) {
        s16x8 a = *(const s16x8*)(wq + (size_t)(mw + low4) * CIN + k0 + quad * 8);
#pragma unroll
        for (int t = 0; t < 4; ++t) {
            s16x8 bfr = *(const s16x8*)(xT + (size_t)(n0 + t * 16 + low4) * CIN + k0 + quad * 8);
            acc[t] = __builtin_amdgcn_mfma_f32_16x16x32_bf16(a, bfr, acc[t], 0, 0, 0);
        }
    }
#pragma unroll
    for (int t = 0; t < 4; ++t) {
        int nG = n0 + t * 16 + low4;
        int b = nG >> 12, n = nG & 4095;
#pragma unroll
        for (int r = 0; r < 4; ++r) {
            int o = mw + quad * 4 + r;
            float v = acc[t][r];
            if (o < 128) {
                int head = o >> 5, ch = o & 31;
                Q[((size_t)(b * 4 + head) * NPOS + n) * 32 + ch] = f2bf(v * QSCALE);
            } else if (o < 256) {
                int o2 = o - 128; int head = o2 >> 5, ch = o2 & 31;
                K[((size_t)(b * 4 + head) * NPOS + n) * 32 + ch] = f2bf(v);
            } else {
                int o2 = o - 256; int head = o2 >> 5, ch = o2 & 31;
                V[((size_t)((b * 4 + head) * 32 + ch)) * NPOS + n] = f2bf(v);
            }
        }
    }
}

// ---------------- kernel 4: attention (flash-style, no-max softmax) ----------------
// grid: bh(16) x qtile(64);  block: 4 waves, each wave owns 16 queries.
// No block barriers: the P transpose tile is wave-private; LDS ops within a
// wave execute in order (HW), so write->read needs no sync.
// P row stride 72 shorts: quad write stride = 4*72 = 288 shorts = 144 dwords
// == 16 mod 32 banks -> 2-way (free, m136); A-frag reads 16B-aligned.
#define PSTRIDE 72
__global__ __launch_bounds__(256) void k_attn(const unsigned short* __restrict__ Q,
                                              const unsigned short* __restrict__ K,
                                              const unsigned short* __restrict__ V,
                                              unsigned short* __restrict__ attnO) {
    __shared__ unsigned short pT[4][16 * PSTRIDE];
    int bh = blockIdx.x >> 6;
    int qt = blockIdx.x & 63;
    int wid = threadIdx.x >> 6, lane = threadIdx.x & 63;
    int quad = lane >> 4, low4 = lane & 15;
    int q0 = qt * 64 + wid * 16;
    const unsigned short* Qp = Q + (size_t)bh * NPOS * 32;
    const unsigned short* Kp = K + (size_t)bh * NPOS * 32 + low4 * 32 + quad * 8;
    const unsigned short* Vp = V + (size_t)bh * 32 * NPOS;
    const unsigned short* vrow0 = Vp + (size_t)low4 * NPOS + quad * 8;
    const unsigned short* vrow1 = Vp + (size_t)(low4 + 16) * NPOS + quad * 8;

    s16x8 aq = *(const s16x8*)(Qp + (size_t)(q0 + low4) * 32 + quad * 8);
    f32x4 oacc0 = {}, oacc1 = {}, lsum = {};
    unsigned short* myP = &pT[wid][0];
    unsigned short* wrP = myP + quad * 4 * PSTRIDE + low4;   // write base: row=quad*4+r, col=low4
    const unsigned short* rdP = myP + low4 * PSTRIDE + quad * 8;  // A-frag read base

    for (int k0 = 0; k0 < NPOS; k0 += 64) {
        // ---- all global loads first (K frags + V frags) for latency hiding ----
        const unsigned short* kb = Kp + (size_t)k0 * 32;
        s16x8 bk0 = *(const s16x8*)(kb);
        s16x8 bk1 = *(const s16x8*)(kb + 16 * 32);
        s16x8 bk2 = *(const s16x8*)(kb + 32 * 32);
        s16x8 bk3 = *(const s16x8*)(kb + 48 * 32);
        s16x8 bv00 = *(const s16x8*)(vrow0 + k0);
        s16x8 bv01 = *(const s16x8*)(vrow0 + k0 + 32);
        s16x8 bv10 = *(const s16x8*)(vrow1 + k0);
        s16x8 bv11 = *(const s16x8*)(vrow1 + k0 + 32);

        // ---- S = Q K^T for 16q x 64k ----
        f32x4 s0 = {}, s1 = {}, s2 = {}, s3 = {};
        s0 = __builtin_amdgcn_mfma_f32_16x16x32_bf16(aq, bk0, s0, 0, 0, 0);
        s1 = __builtin_amdgcn_mfma_f32_16x16x32_bf16(aq, bk1, s1, 0, 0, 0);
        s2 = __builtin_amdgcn_mfma_f32_16x16x32_bf16(aq, bk2, s2, 0, 0, 0);
        s3 = __builtin_amdgcn_mfma_f32_16x16x32_bf16(aq, bk3, s3, 0, 0, 0);

        // ---- exp + transpose through wave-private LDS ----
#pragma unroll
        for (int r = 0; r < 4; ++r) {
            float p0 = __expf(s0[r]);
            float p1 = __expf(s1[r]);
            float p2 = __expf(s2[r]);
            float p3 = __expf(s3[r]);
            lsum[r] += (p0 + p1) + (p2 + p3);
            unsigned short* w = wrP + r * PSTRIDE;
            w[0]  = f2bf(p0);
            w[16] = f2bf(p1);
            w[32] = f2bf(p2);
            w[48] = f2bf(p3);
        }
        // in-wave DS ordering guarantees the reads below see the writes above
        s16x8 ap0 = *(const s16x8*)(rdP);
        s16x8 ap1 = *(const s16x8*)(rdP + 32);

        // ---- O += P V ----
        oacc0 = __builtin_amdgcn_mfma_f32_16x16x32_bf16(ap0, bv00, oacc0, 0, 0, 0);
        oacc1 = __builtin_amdgcn_mfma_f32_16x16x32_bf16(ap0, bv10, oacc1, 0, 0, 0);
        oacc0 = __builtin_amdgcn_mfma_f32_16x16x32_bf16(ap1, bv01, oacc0, 0, 0, 0);
        oacc1 = __builtin_amdgcn_mfma_f32_16x16x32_bf16(ap1, bv11, oacc1, 0, 0, 0);
    }

    // reduce lsum over the 16 lanes sharing a quad (keys mod 16)
#pragma unroll
    for (int r = 0; r < 4; ++r) {
        float v = lsum[r];
        v += __shfl_xor(v, 1);
        v += __shfl_xor(v, 2);
        v += __shfl_xor(v, 4);
        v += __shfl_xor(v, 8);
        lsum[r] = v;
    }
    int b = bh >> 2, head = bh & 3;
#pragma unroll
    for (int r = 0; r < 4; ++r) {
        float inv = 1.0f / lsum[r];
        int n = q0 + quad * 4 + r;
        size_t base = ((size_t)(b * NPOS + n)) * CHID + head * 32;
        attnO[base + low4]      = f2bf(oacc0[r] * inv);
        attnO[base + low4 + 16] = f2bf(oacc1[r] * inv);
    }
}

// ---------------- kernel 5: output projection GEMM + bias ----------------
__global__ __launch_bounds__(256) void k_out(const unsigned short* __restrict__ wo,
                                             const unsigned short* __restrict__ attnO,
                                             const float* __restrict__ bias,
                                             float* __restrict__ out) {
    int mt = blockIdx.x & 3;        // 256/64
    int nt = blockIdx.x >> 2;       // 0..255
    int wid = threadIdx.x >> 6, lane = threadIdx.x & 63;
    int quad = lane >> 4, low4 = lane & 15;
    int mw = mt * 64 + wid * 16;
    int n0 = nt * 64;
    f32x4 acc[4] = {};
#pragma unroll
    for (int k0 = 0; k0 < CHID; k0 += 32) {
        s16x8 a = *(const s16x8*)(wo + (size_t)(mw + low4) * CHID + k0 + quad * 8);
#pragma unroll
        for (int t = 0; t < 4; ++t) {
            s16x8 bfr = *(const s16x8*)(attnO + (size_t)(n0 + t * 16 + low4) * CHID + k0 + quad * 8);
            acc[t] = __builtin_amdgcn_mfma_f32_16x16x32_bf16(a, bfr, acc[t], 0, 0, 0);
        }
    }
#pragma unroll
    for (int t = 0; t < 4; ++t) {
        int nG = n0 + t * 16 + low4;
        int b = nG >> 12, n = nG & 4095;
#pragma unroll
        for (int r = 0; r < 4; ++r) {
            int o = mw + quad * 4 + r;
            out[((size_t)(b * CIN + o)) * NPOS + n] = acc[t][r] + bias[o];
        }
    }
}

extern "C" void kernel_launch(void* const* d_in, const int* in_sizes, int n_in,
                              void* d_out, int out_size, void* d_ws, size_t ws_size,
                              hipStream_t stream) {
    const float* x    = (const float*)d_in[0];
    const float* wqkv = (const float*)d_in[1];
    const float* wout = (const float*)d_in[2];
    const float* bout = (const float*)d_in[3];
    float* out = (float*)d_out;

    unsigned short* Q       = (unsigned short*)d_ws;
    unsigned short* K       = Q + (size_t)BH * NPOS * 32;       // +4 MB
    unsigned short* V       = K + (size_t)BH * NPOS * 32;       // +4 MB
    unsigned short* attnO   = V + (size_t)BH * 32 * NPOS;       // +4 MB
    unsigned short* xT      = attnO + (size_t)NTOT * CHID;      // +4 MB
    unsigned short* wqkv_bf = xT + (size_t)NTOT * CIN;          // +8 MB
    unsigned short* wout_bf = wqkv_bf + QKV_O * CIN;            // +192 KB
    // total ~24.3 MB of ws

    k_convert_w<<<(QKV_O * CIN + 255) / 256, 256, 0, stream>>>(wqkv, wout, wqkv_bf, wout_bf);
    k_transpose_x<<<NB * (CIN / 32) * (NPOS / 32), 256, 0, stream>>>(x, xT);
    k_qkv<<<(QKV_O / 64) * (NTOT / 64), 256, 0, stream>>>(wqkv_bf, xT, Q, K, V);
    k_attn<<<BH * (NPOS / 64), 256, 0, stream>>>(Q, K, V, attnO);
    k_out<<<(CIN / 64) * (NTOT / 64), 256, 0, stream>>>(wout_bf, attnO, bout, out);
}